// Round 8
// baseline (920.463 us; speedup 1.0000x reference)
//
#include <hip/hip_runtime.h>
#include <hip/hip_bf16.h>

#define EPS 1e-5f

// ---------------------------------------------------------------- stats ----
__global__ __launch_bounds__(256) void stats_kernel(
    const float* __restrict__ buf, float* __restrict__ mean,
    float* __restrict__ rstd) {
  int bc = blockIdx.x;
  const float* ch = buf + (size_t)bc * 32768;
  float s = 0.f, ss = 0.f;
  for (int i = threadIdx.x; i < 32768; i += 256) {
    float v = ch[i];
    s += v; ss += v * v;
  }
  for (int o = 32; o; o >>= 1) {
    s += __shfl_down(s, o);
    ss += __shfl_down(ss, o);
  }
  __shared__ float sb[4], ssb[4];
  int wid = threadIdx.x >> 6, lane = threadIdx.x & 63;
  if (lane == 0) { sb[wid] = s; ssb[wid] = ss; }
  __syncthreads();
  if (threadIdx.x == 0) {
    float S = 0.f, SS = 0.f;
    for (int w = 0; w < 4; ++w) { S += sb[w]; SS += ssb[w]; }
    float m = S * (1.f / 32768.f);
    float var = SS * (1.f / 32768.f) - m * m;
    mean[bc] = m;
    rstd[bc] = rsqrtf(var + EPS);
  }
}

// ------------------------------------------------------------------- SE ----
__global__ void se_kernel(const float* __restrict__ mean_x,
                          const float* __restrict__ w1, const float* __restrict__ b1,
                          const float* __restrict__ w2, const float* __restrict__ b2,
                          float* __restrict__ dw) {
  __shared__ float hbuf[32];
  int t = threadIdx.x;
  if (t < 32) {
    int b = t >> 4, j = t & 15;
    float a = b1[j];
    for (int c = 0; c < 64; ++c) a += mean_x[b * 64 + c] * w1[j * 64 + c];
    hbuf[t] = a >= 0.f ? a : 0.2f * a;
  }
  __syncthreads();
  if (t < 2) {
    int b = t;
    float l0 = b2[0], l1 = b2[1];
    for (int j = 0; j < 16; ++j) {
      float h = hbuf[b * 16 + j];
      l0 += h * w2[j];
      l1 += h * w2[16 + j];
    }
    float m = fmaxf(l0, l1);
    float e0 = __expf(l0 - m), e1 = __expf(l1 - m);
    float inv = 1.f / (e0 + e1);
    dw[b * 2 + 0] = e0 * inv;
    dw[b * 2 + 1] = e1 * inv;
  }
}

// --------------------------------------------- transpose w_def -> [k][i][o]
__global__ __launch_bounds__(256) void prep_wdef(const float* __restrict__ w_def,
                                                 float* __restrict__ wTd) {
  int idx = blockIdx.x * 256 + threadIdx.x;  // 27*32*32 = 27648
  if (idx < 27648) {
    int o = idx & 31, rest = idx >> 5;
    int i = rest & 31, k = rest >> 5;
    wTd[idx] = w_def[(size_t)(o * 32 + i) * 27 + k];
  }
}

// ------------------- fused inorm+lrelu+1x1 (64->32), o-split x4 -----------
__global__ __launch_bounds__(256) void first_conv_kernel(
    const float* __restrict__ x, const float* __restrict__ w,   // [32,64]
    const float* __restrict__ bias,
    const float* __restrict__ meanp, const float* __restrict__ rstdp,
    float* __restrict__ f_cp, float* __restrict__ f_pc) {
  int og = blockIdx.x >> 8;
  int chunk = blockIdx.x & 255;
  int vg = chunk * 256 + threadIdx.x;
  int b = vg >> 15, p = vg & 32767;
  float acc[8];
#pragma unroll
  for (int o = 0; o < 8; ++o) acc[o] = 0.f;
  const float* xb = x + ((size_t)b * 64) * 32768;
  const float* wg = w + (size_t)og * 8 * 64;
  for (int i = 0; i < 64; ++i) {
    float v = xb[(size_t)i * 32768 + p];
    float m = meanp[b * 64 + i], r = rstdp[b * 64 + i];
    v = (v - m) * r;
    v = v >= 0.f ? v : 0.2f * v;
#pragma unroll
    for (int o = 0; o < 8; ++o) acc[o] = fmaf(wg[o * 64 + i], v, acc[o]);
  }
#pragma unroll
  for (int o = 0; o < 8; ++o) {
    acc[o] += bias[og * 8 + o];
    f_cp[((size_t)b * 32 + og * 8 + o) * 32768 + p] = acc[o];
  }
  float4 v0 = make_float4(acc[0], acc[1], acc[2], acc[3]);
  float4 v1 = make_float4(acc[4], acc[5], acc[6], acc[7]);
  float* pc = f_pc + ((size_t)b * 32768 + p) * 32 + og * 8;
  *(float4*)pc = v0;
  *(float4*)(pc + 4) = v1;
}

// ----------------------------------------------------- tiled 3x3x3 conv ----
// v3: IC-blocked phases (8 ic/phase, 4 phases, ONE barrier per phase) with
// T14 issue-early/write-late staging: issue next phase's 24 global loads,
// compute current phase's 8 ics (hides load latency), then ds_write + barrier.
// LDS tileS[2][8][720] = 46 KB -> 3 blocks/CU. Weights: wave-uniform s_loads.
// icl compute loop kept runtime (I-cache); tap offsets are compile-time.
template <int OCG, bool REFLECT, bool NORM_IN>
__global__ __launch_bounds__(256) void conv3_kernel(
    const float* __restrict__ in,    // [B,32,32768]
    const float* __restrict__ w,     // [OC_total,32,27]
    const float* __restrict__ bias,  // [OC_total]
    const float* __restrict__ meanp, const float* __restrict__ rstdp,
    float* __restrict__ out,         // [B,OC_total,32768]
    int IC, int OC_total) {
  int bid = blockIdx.x;
  int tile = bid & 127;
  int rem = bid >> 7;
  int b = rem & 1;
  int og = rem >> 1;
  int tz = tile >> 4, ty = (tile >> 2) & 3, tx = tile & 3;
  int z0 = tz * 4, y0 = ty * 8, x0 = tx * 8;

  int tid = threadIdx.x;
  int lz = tid >> 6, ly = (tid >> 3) & 7, lx = tid & 7;

  __shared__ float tileS[2][8][720];  // [buf][icl][6*10*12]

  int s0 = tid, s1 = tid + 256, s2 = tid + 512;
  int g0 = 0, g1 = 0, g2 = 0;
  bool a0 = false, a1 = false, a2 = false;
  bool k0 = true, k1 = true, k2 = true;
#define DESC(S, G, A, K)                                            \
  {                                                                 \
    int hz = (S) / 120;                                             \
    int rr = (S) - hz * 120;                                        \
    int hy = rr / 12;                                               \
    int hx = rr - hy * 12;                                          \
    if ((S) < 720 && hx < 10) {                                     \
      int gz = z0 + hz - 1, gy = y0 + hy - 1, gx = x0 + hx - 1;     \
      if (REFLECT) {                                                \
        gz = gz < 0 ? -gz : (gz > 31 ? 62 - gz : gz);               \
        gy = gy < 0 ? -gy : (gy > 31 ? 62 - gy : gy);               \
        gx = gx < 0 ? -gx : (gx > 31 ? 62 - gx : gx);               \
      } else {                                                      \
        K = (unsigned)gz < 32u && (unsigned)gy < 32u &&             \
            (unsigned)gx < 32u;                                     \
        if (!(K)) { gz = 0; gy = 0; gx = 0; }                       \
      }                                                             \
      G = (gz * 32 + gy) * 32 + gx;                                 \
      A = true;                                                     \
    }                                                               \
  }
  DESC(s0, g0, a0, k0)
  DESC(s1, g1, a1, k1)
  DESC(s2, g2, a2, k2)
#undef DESC

  const float* inb = in + ((size_t)b * 32) * 32768;
  int ocbase = og * OCG;

  float acc[OCG];
#pragma unroll
  for (int o = 0; o < OCG; ++o) acc[o] = 0.f;

  float vv0[8], vv1[8], vv2[8];

  // issue 24 global loads for ic block starting at PB
#define LOADV(PB)                                                   \
  _Pragma("unroll")                                                 \
  for (int icl = 0; icl < 8; ++icl) {                               \
    const float* ch = inb + (size_t)((PB) + icl) * 32768;           \
    if (a0) vv0[icl] = k0 ? ch[g0] : 0.f;                           \
    if (a1) vv1[icl] = k1 ? ch[g1] : 0.f;                           \
    if (a2) vv2[icl] = k2 ? ch[g2] : 0.f;                           \
  }

  // norm + write staged regs to LDS buffer BUF
#define WRITEV(BUF, PB)                                             \
  _Pragma("unroll")                                                 \
  for (int icl = 0; icl < 8; ++icl) {                               \
    float m = 0.f, r = 1.f;                                         \
    if (NORM_IN) {                                                  \
      m = meanp[b * 32 + (PB) + icl];                               \
      r = rstdp[b * 32 + (PB) + icl];                               \
    }                                                               \
    float* dst = &tileS[BUF][icl][0];                               \
    if (a0) {                                                       \
      float v = vv0[icl];                                           \
      if (NORM_IN) { v = (v - m) * r; v = v >= 0.f ? v : 0.2f * v; }\
      dst[s0] = v;                                                  \
    }                                                               \
    if (a1) {                                                       \
      float v = vv1[icl];                                           \
      if (NORM_IN) { v = (v - m) * r; v = v >= 0.f ? v : 0.2f * v; }\
      dst[s1] = v;                                                  \
    }                                                               \
    if (a2) {                                                       \
      float v = vv2[icl];                                           \
      if (NORM_IN) { v = (v - m) * r; v = v >= 0.f ? v : 0.2f * v; }\
      dst[s2] = v;                                                  \
    }                                                               \
  }

  int base = lz * 120 + ly * 12 + lx;

  LOADV(0)
  WRITEV(0, 0)
  __syncthreads();

  for (int ph = 0; ph < 4; ++ph) {
    int cur = ph & 1;
    if (ph < 3) LOADV((ph + 1) * 8)

    // compute 8 ics of this phase (icl runtime loop, fits I-cache)
    for (int icl = 0; icl < 8; ++icl) {
      const float* src = &tileS[cur][icl][0];
      float tap[27];
#pragma unroll
      for (int t = 0; t < 27; ++t) {
        int dz = t / 9, dy = (t / 3) % 3, dx = t % 3;
        tap[t] = src[base + dz * 120 + dy * 12 + dx];
      }
      const float* wic = w + (size_t)(ph * 8 + icl) * 27;
#pragma unroll
      for (int o = 0; o < OCG; ++o) {
        const float* wo = wic + (size_t)(ocbase + o) * 32 * 27;  // wave-uniform
#pragma unroll
        for (int t = 0; t < 27; ++t) acc[o] = fmaf(wo[t], tap[t], acc[o]);
      }
    }

    if (ph < 3) WRITEV(cur ^ 1, (ph + 1) * 8)
    __syncthreads();
  }
#undef LOADV
#undef WRITEV

  int p = ((z0 + lz) * 32 + (y0 + ly)) * 32 + (x0 + lx);
#pragma unroll
  for (int o = 0; o < OCG; ++o) {
    int oc = ocbase + o;
    out[((size_t)b * OC_total + oc) * 32768 + p] = acc[o] + bias[oc];
  }
}

// --------------------------------------------------------------- deform ----
// Thread-per-position, 3-way tap split. Gather: 8 corners x 8 float4 into
// v[32] (VGPRs). Matmul: wave-uniform weight loads from wTd[k][i][o];
// i outer / o inner gives 32 independent FMAs per step. No LDS/shuffles.
__global__ __launch_bounds__(256) void deform_kernel(
    const float* __restrict__ f_pc,  // [B,32768,32]
    const float* __restrict__ offs,  // [B,81,32768]
    const float* __restrict__ wTd,   // [27,32,32] (k,i,o)
    float* __restrict__ part) {      // [3,B,32,32768]
  int bid = blockIdx.x;
  int kg = bid >> 8;                 // 0..2
  int tile = bid & 255;
  int vg = tile * 256 + threadIdx.x;
  int b = vg >> 15, p = vg & 32767;
  int z = p >> 10, y = (p >> 5) & 31, x = p & 31;
  const float* fb = f_pc + (((size_t)b) << 15) * 32;
  const float* ob = offs + (((size_t)b * 81) << 15);
  int kz = kg - 1;

  float acc[32];
#pragma unroll
  for (int o = 0; o < 32; ++o) acc[o] = 0.f;

  for (int kk = 0; kk < 9; ++kk) {
    int k = kg * 9 + kk;
    int ky = kk / 3 - 1, kx = kk % 3 - 1;

    float oz = ob[(size_t)(k * 3 + 0) * 32768 + p];
    float oy = ob[(size_t)(k * 3 + 1) * 32768 + p];
    float ox = ob[(size_t)(k * 3 + 2) * 32768 + p];
    float pz = (float)(z + kz) + oz;
    float py = (float)(y + ky) + oy;
    float px = (float)(x + kx) + ox;
    float fz = floorf(pz), fy = floorf(py), fxx = floorf(px);
    int iz0 = (int)fz, iy0 = (int)fy, ix0 = (int)fxx;
    float rz = pz - fz, ry = py - fy, rx = px - fxx;

    float v[32];
#pragma unroll
    for (int c = 0; c < 32; ++c) v[c] = 0.f;
#pragma unroll
    for (int corner = 0; corner < 8; ++corner) {
      int dz = corner >> 2, dy = (corner >> 1) & 1, dxx = corner & 1;
      int iz = iz0 + dz, iy = iy0 + dy, ix = ix0 + dxx;
      bool okb = (unsigned)iz < 32u && (unsigned)iy < 32u && (unsigned)ix < 32u;
      float wt = (dz ? rz : 1.f - rz) * (dy ? ry : 1.f - ry) *
                 (dxx ? rx : 1.f - rx);
      if (okb) {
        const float4* src =
            (const float4*)(fb + (size_t)((iz * 32 + iy) * 32 + ix) * 32);
#pragma unroll
        for (int q = 0; q < 8; ++q) {
          float4 u = src[q];
          v[q * 4 + 0] = fmaf(wt, u.x, v[q * 4 + 0]);
          v[q * 4 + 1] = fmaf(wt, u.y, v[q * 4 + 1]);
          v[q * 4 + 2] = fmaf(wt, u.z, v[q * 4 + 2]);
          v[q * 4 + 3] = fmaf(wt, u.w, v[q * 4 + 3]);
        }
      }
    }
    const float* wk = wTd + (size_t)k * 1024;  // wave-uniform base
#pragma unroll
    for (int i = 0; i < 32; ++i) {
      float vi = v[i];
      const float* wr = wk + i * 32;
#pragma unroll
      for (int o = 0; o < 32; ++o) acc[o] = fmaf(wr[o], vi, acc[o]);
    }
  }
  float* obp = part + (((size_t)kg * 2 + b) * 32) * 32768 + p;
#pragma unroll
  for (int o = 0; o < 32; ++o) obp[(size_t)o * 32768] = acc[o];
}

// ------------------- combine (3 partials + alpha) + partial stats ---------
__global__ __launch_bounds__(256) void combine_kernel(
    const float* __restrict__ part, const float* __restrict__ alpha,
    const float* __restrict__ dw, float* __restrict__ comb,
    float* __restrict__ partial) {   // [256][2]
  int blk = blockIdx.x;              // 64 bc x 4 quarters
  int bc = blk >> 2, qt = blk & 3;
  int b = bc >> 5;
  float d0 = dw[b * 2 + 0], d1 = dw[b * 2 + 1];
  const float* p0 = part + (size_t)(bc) * 32768;
  const float* p1 = part + (size_t)(64 + bc) * 32768;
  const float* p2 = part + (size_t)(128 + bc) * 32768;
  const float* al = alpha + (size_t)bc * 32768;
  float* cb = comb + (size_t)bc * 32768;
  float s = 0.f, ss = 0.f;
  int i0 = qt * 8192;
  for (int i = i0 + threadIdx.x; i < i0 + 8192; i += 256) {
    float v = d0 * (p0[i] + p1[i] + p2[i]) + d1 * al[i];
    cb[i] = v;
    s += v; ss += v * v;
  }
  for (int o = 32; o; o >>= 1) {
    s += __shfl_down(s, o);
    ss += __shfl_down(ss, o);
  }
  __shared__ float sb[4], ssb[4];
  int wid = threadIdx.x >> 6, lane = threadIdx.x & 63;
  if (lane == 0) { sb[wid] = s; ssb[wid] = ss; }
  __syncthreads();
  if (threadIdx.x == 0) {
    float S = 0.f, SS = 0.f;
    for (int w = 0; w < 4; ++w) { S += sb[w]; SS += ssb[w]; }
    partial[blk * 2 + 0] = S;
    partial[blk * 2 + 1] = SS;
  }
}

__global__ void finalize_kernel(const float* __restrict__ partial,
                                float* __restrict__ mean, float* __restrict__ rstd) {
  int t = threadIdx.x;  // 64 = bc
  if (t < 64) {
    float S = 0.f, SS = 0.f;
    for (int q = 0; q < 4; ++q) {
      S += partial[(t * 4 + q) * 2 + 0];
      SS += partial[(t * 4 + q) * 2 + 1];
    }
    float m = S * (1.f / 32768.f);
    float var = SS * (1.f / 32768.f) - m * m;
    mean[t] = m;
    rstd[t] = rsqrtf(var + EPS);
  }
}

// ------------------- fused inorm+lrelu+1x1 (32->32), o-split x4 -----------
__global__ __launch_bounds__(256) void last_conv_kernel(
    const float* __restrict__ comb, const float* __restrict__ w,  // [32,32]
    const float* __restrict__ bias,
    const float* __restrict__ meanp, const float* __restrict__ rstdp,
    float* __restrict__ out) {
  int og = blockIdx.x >> 8;
  int chunk = blockIdx.x & 255;
  int vg = chunk * 256 + threadIdx.x;
  int b = vg >> 15, p = vg & 32767;
  float acc[8];
#pragma unroll
  for (int o = 0; o < 8; ++o) acc[o] = 0.f;
  const float* cb = comb + ((size_t)b * 32) * 32768;
  const float* wg = w + (size_t)og * 8 * 32;
  for (int i = 0; i < 32; ++i) {
    float v = cb[(size_t)i * 32768 + p];
    float m = meanp[b * 32 + i], r = rstdp[b * 32 + i];
    v = (v - m) * r;
    v = v >= 0.f ? v : 0.2f * v;
#pragma unroll
    for (int o = 0; o < 8; ++o) acc[o] = fmaf(wg[o * 32 + i], v, acc[o]);
  }
#pragma unroll
  for (int o = 0; o < 8; ++o)
    out[((size_t)b * 32 + og * 8 + o) * 32768 + p] = acc[o] + bias[og * 8 + o];
}

// ---------------------------------------------------------------- launch ---
extern "C" void kernel_launch(void* const* d_in, const int* in_sizes, int n_in,
                              void* d_out, int out_size, void* d_ws, size_t ws_size,
                              hipStream_t stream) {
  (void)in_sizes; (void)n_in; (void)out_size; (void)ws_size;
  const float* x       = (const float*)d_in[0];
  const float* w_first = (const float*)d_in[1];
  const float* b_first = (const float*)d_in[2];
  const float* w_na    = (const float*)d_in[3];
  const float* b_na    = (const float*)d_in[4];
  const float* w_last  = (const float*)d_in[5];
  const float* b_last  = (const float*)d_in[6];
  const float* w_fc1   = (const float*)d_in[7];
  const float* b_fc1   = (const float*)d_in[8];
  const float* w_fc2   = (const float*)d_in[9];
  const float* b_fc2   = (const float*)d_in[10];
  const float* w_off   = (const float*)d_in[11];
  const float* b_off   = (const float*)d_in[12];
  const float* w_def   = (const float*)d_in[13];
  float* out = (float*)d_out;

  float* ws = (float*)d_ws;
  float* mean_x  = ws + 0;        // 128
  float* rstd_x  = ws + 128;      // 128
  float* dwp     = ws + 256;      // 4
  float* mean_f  = ws + 272;      // 64
  float* rstd_f  = ws + 336;      // 64
  float* mean_c  = ws + 400;      // 64
  float* rstd_c  = ws + 464;      // 64
  float* partial = ws + 528;      // 512
  size_t off0 = 2048;
  float* wTd   = ws + off0;                       // 27,648
  float* f_cp  = ws + off0 + 28672;               // 2,097,152
  float* f_pc  = f_cp + 2097152;                  // 2,097,152
  float* offb  = f_pc + 2097152;                  // 5,308,416
  float* alpha = offb + 5308416;                  // 2,097,152
  float* part  = alpha + 2097152;                 // 6,291,456
  float* comb  = part + 6291456;                  // 2,097,152

  // 1. stats of x (also SE global-avg-pool) + weight transpose prep
  hipLaunchKernelGGL(stats_kernel, dim3(128), dim3(256), 0, stream, x, mean_x, rstd_x);
  hipLaunchKernelGGL(prep_wdef, dim3(108), dim3(256), 0, stream, w_def, wTd);
  // 2. SE gate -> dw
  hipLaunchKernelGGL(se_kernel, dim3(1), dim3(64), 0, stream,
                     mean_x, w_fc1, b_fc1, w_fc2, b_fc2, dwp);
  // 3. f = conv1x1(lrelu(inorm(x))), two layouts, o-split x4
  hipLaunchKernelGGL(first_conv_kernel, dim3(1024), dim3(256), 0, stream,
                     x, w_first, b_first, mean_x, rstd_x, f_cp, f_pc);
  // 4. stats of f
  hipLaunchKernelGGL(stats_kernel, dim3(64), dim3(256), 0, stream, f_cp, mean_f, rstd_f);
  // 5. off = conv3x3x3(f), zero pad, 32->81 (3 og of 27)
  hipLaunchKernelGGL((conv3_kernel<27, false, false>), dim3(128 * 2 * 3), dim3(256), 0, stream,
                     f_cp, w_off, b_off, nullptr, nullptr, offb, 32, 81);
  // 6. alpha = conv3x3x3(lrelu(inorm(f))), reflect pad (2 og of 16)
  hipLaunchKernelGGL((conv3_kernel<16, true, true>), dim3(128 * 2 * 2), dim3(256), 0, stream,
                     f_cp, w_na, b_na, mean_f, rstd_f, alpha, 32, 32);
  // 7. belta partials (deform), SGPR-weight matmul, no LDS
  hipLaunchKernelGGL(deform_kernel, dim3(768), dim3(256), 0, stream,
                     f_pc, offb, wTd, part);
  // 8. comb = dw0*belta + dw1*alpha, partial stats
  hipLaunchKernelGGL(combine_kernel, dim3(256), dim3(256), 0, stream,
                     part, alpha, dwp, comb, partial);
  hipLaunchKernelGGL(finalize_kernel, dim3(1), dim3(64), 0, stream,
                     partial, mean_c, rstd_c);
  // 9. out = conv1x1(lrelu(inorm(comb)))
  hipLaunchKernelGGL(last_conv_kernel, dim3(1024), dim3(256), 0, stream,
                     comb, w_last, b_last, mean_c, rstd_c, out);
}

// Round 11
// 810.605 us; speedup vs baseline: 1.1355x; 1.1355x over previous
//
#include <hip/hip_runtime.h>
#include <hip/hip_bf16.h>

#define EPS 1e-5f

// ---------------------------------------------------------------- stats ----
__global__ __launch_bounds__(256) void stats_kernel(
    const float* __restrict__ buf, float* __restrict__ mean,
    float* __restrict__ rstd) {
  int bc = blockIdx.x;
  const float* ch = buf + (size_t)bc * 32768;
  float s = 0.f, ss = 0.f;
  for (int i = threadIdx.x; i < 32768; i += 256) {
    float v = ch[i];
    s += v; ss += v * v;
  }
  for (int o = 32; o; o >>= 1) {
    s += __shfl_down(s, o);
    ss += __shfl_down(ss, o);
  }
  __shared__ float sb[4], ssb[4];
  int wid = threadIdx.x >> 6, lane = threadIdx.x & 63;
  if (lane == 0) { sb[wid] = s; ssb[wid] = ss; }
  __syncthreads();
  if (threadIdx.x == 0) {
    float S = 0.f, SS = 0.f;
    for (int w = 0; w < 4; ++w) { S += sb[w]; SS += ssb[w]; }
    float m = S * (1.f / 32768.f);
    float var = SS * (1.f / 32768.f) - m * m;
    mean[bc] = m;
    rstd[bc] = rsqrtf(var + EPS);
  }
}

// ------------------------------------------------------------------- SE ----
__global__ void se_kernel(const float* __restrict__ mean_x,
                          const float* __restrict__ w1, const float* __restrict__ b1,
                          const float* __restrict__ w2, const float* __restrict__ b2,
                          float* __restrict__ dw) {
  __shared__ float hbuf[32];
  int t = threadIdx.x;
  if (t < 32) {
    int b = t >> 4, j = t & 15;
    float a = b1[j];
    for (int c = 0; c < 64; ++c) a += mean_x[b * 64 + c] * w1[j * 64 + c];
    hbuf[t] = a >= 0.f ? a : 0.2f * a;
  }
  __syncthreads();
  if (t < 2) {
    int b = t;
    float l0 = b2[0], l1 = b2[1];
    for (int j = 0; j < 16; ++j) {
      float h = hbuf[b * 16 + j];
      l0 += h * w2[j];
      l1 += h * w2[16 + j];
    }
    float m = fmaxf(l0, l1);
    float e0 = __expf(l0 - m), e1 = __expf(l1 - m);
    float inv = 1.f / (e0 + e1);
    dw[b * 2 + 0] = e0 * inv;
    dw[b * 2 + 1] = e1 * inv;
  }
}

// --------------------------------------------- transpose w_def -> [k][i][o]
__global__ __launch_bounds__(256) void prep_wdef(const float* __restrict__ w_def,
                                                 float* __restrict__ wTd) {
  int idx = blockIdx.x * 256 + threadIdx.x;  // 27*32*32 = 27648
  if (idx < 27648) {
    int o = idx & 31, rest = idx >> 5;
    int i = rest & 31, k = rest >> 5;
    wTd[idx] = w_def[(size_t)(o * 32 + i) * 27 + k];
  }
}

// ------------------- fused inorm+lrelu+1x1 (64->32), o-split x4 -----------
__global__ __launch_bounds__(256) void first_conv_kernel(
    const float* __restrict__ x, const float* __restrict__ w,   // [32,64]
    const float* __restrict__ bias,
    const float* __restrict__ meanp, const float* __restrict__ rstdp,
    float* __restrict__ f_cp, float* __restrict__ f_pc) {
  int og = blockIdx.x >> 8;
  int chunk = blockIdx.x & 255;
  int vg = chunk * 256 + threadIdx.x;
  int b = vg >> 15, p = vg & 32767;
  float acc[8];
#pragma unroll
  for (int o = 0; o < 8; ++o) acc[o] = 0.f;
  const float* xb = x + ((size_t)b * 64) * 32768;
  const float* wg = w + (size_t)og * 8 * 64;
  for (int i = 0; i < 64; ++i) {
    float v = xb[(size_t)i * 32768 + p];
    float m = meanp[b * 64 + i], r = rstdp[b * 64 + i];
    v = (v - m) * r;
    v = v >= 0.f ? v : 0.2f * v;
#pragma unroll
    for (int o = 0; o < 8; ++o) acc[o] = fmaf(wg[o * 64 + i], v, acc[o]);
  }
#pragma unroll
  for (int o = 0; o < 8; ++o) {
    acc[o] += bias[og * 8 + o];
    f_cp[((size_t)b * 32 + og * 8 + o) * 32768 + p] = acc[o];
  }
  float4 v0 = make_float4(acc[0], acc[1], acc[2], acc[3]);
  float4 v1 = make_float4(acc[4], acc[5], acc[6], acc[7]);
  float* pc = f_pc + ((size_t)b * 32768 + p) * 32 + og * 8;
  *(float4*)pc = v0;
  *(float4*)(pc + 4) = v1;
}

// ---------------------------- off-conv 3x3x3, zero-pad, x-paired ----------
// Tile 4(z)x8(y)x16(x); each thread computes outputs (x, x+1): per (dz,dy)
// row two aligned ds_read_b64 give taps t0..t3 feeding 54 independent FMAs
// (9 oc x 2 out x 3 dx) -> high FMA:LDS ratio. Halo [6][10][18] = 4320 B,
// double-buffered (8.6 KB). One barrier per ic; load-early/write-late.
// Weights wave-uniform scalar loads. Grid: 64 tiles x 2 b x 9 og = 1152.
__global__ __launch_bounds__(256) void conv3_off_kernel(
    const float* __restrict__ in,    // [B,32,32768] (f_cp)
    const float* __restrict__ w,     // [81,32,27]
    const float* __restrict__ bias,  // [81]
    float* __restrict__ out) {       // [B,81,32768]
  int bid = blockIdx.x;
  int tile = bid & 63;
  int rem = bid >> 6;
  int b = rem & 1;
  int og = rem >> 1;                 // 0..8
  int tz = tile >> 3, ty = (tile >> 1) & 3, tx = tile & 1;
  int z0 = tz * 4, y0 = ty * 8, x0 = tx * 16;

  int tid = threadIdx.x;
  int lz = tid >> 6, ly = (tid >> 3) & 7, lx2 = tid & 7;

  __shared__ float tileS[2][1080];   // [6][10][18]

  int gA0 = 0, gA1 = 0, gA2 = 0, gA3 = 0, gA4 = 0;
  bool kA0 = true, kA1 = true, kA2 = true, kA3 = true, kA4 = true;
  bool aA4 = false;
#define DESC5(S, G, K, A)                                           \
  {                                                                 \
    int hz = (S) / 180, rr = (S) - hz * 180;                        \
    int hy = rr / 18, hx = rr - hy * 18;                            \
    int gz = z0 + hz - 1, gy = y0 + hy - 1, gx = x0 + hx - 1;       \
    K = (unsigned)gz < 32u && (unsigned)gy < 32u &&                 \
        (unsigned)gx < 32u;                                         \
    G = K ? (gz * 32 + gy) * 32 + gx : 0;                           \
    A = true;                                                       \
  }
  bool dummy;
  DESC5(tid, gA0, kA0, dummy)
  DESC5(tid + 256, gA1, kA1, dummy)
  DESC5(tid + 512, gA2, kA2, dummy)
  DESC5(tid + 768, gA3, kA3, dummy)
  if (tid + 1024 < 1080) DESC5(tid + 1024, gA4, kA4, aA4)
#undef DESC5

  const float* inb = in + ((size_t)b * 32) * 32768;
  int ocbase = og * 9;

  float acc0[9], acc1[9];
#pragma unroll
  for (int o = 0; o < 9; ++o) { acc0[o] = 0.f; acc1[o] = 0.f; }

  float vv0, vv1, vv2, vv3, vv4;
#define LOADX(ICC)                                                  \
  {                                                                 \
    const float* ch = inb + (size_t)(ICC) * 32768;                  \
    vv0 = kA0 ? ch[gA0] : 0.f;                                      \
    vv1 = kA1 ? ch[gA1] : 0.f;                                      \
    vv2 = kA2 ? ch[gA2] : 0.f;                                      \
    vv3 = kA3 ? ch[gA3] : 0.f;                                      \
    vv4 = (aA4 && kA4) ? ch[gA4] : 0.f;                             \
  }
#define WRITEX(BUF)                                                 \
  {                                                                 \
    float* d = &tileS[BUF][0];                                      \
    d[tid] = vv0;                                                   \
    d[tid + 256] = vv1;                                             \
    d[tid + 512] = vv2;                                             \
    d[tid + 768] = vv3;                                             \
    if (aA4) d[tid + 1024] = vv4;                                   \
  }

  LOADX(0)
  WRITEX(0)
  __syncthreads();

  int rbase = lz * 180 + ly * 18 + 2 * lx2;

  for (int ic = 0; ic < 32; ++ic) {
    int cur = ic & 1;
    if (ic + 1 < 32) LOADX(ic + 1)

    const float* src = &tileS[cur][0];
    const float* wic = w + ((size_t)ocbase * 32 + ic) * 27;
#pragma unroll
    for (int dz = 0; dz < 3; ++dz) {
#pragma unroll
      for (int dy = 0; dy < 3; ++dy) {
        const float* rp = src + rbase + dz * 180 + dy * 18;
        float t0 = rp[0], t1 = rp[1], t2 = rp[2], t3 = rp[3];
        int tb = (dz * 3 + dy) * 3;
#pragma unroll
        for (int o = 0; o < 9; ++o) {
          const float* wr = wic + (size_t)o * 864 + tb;  // wave-uniform
          float w0 = wr[0], w1 = wr[1], w2 = wr[2];
          acc0[o] = fmaf(w2, t2, fmaf(w1, t1, fmaf(w0, t0, acc0[o])));
          acc1[o] = fmaf(w2, t3, fmaf(w1, t2, fmaf(w0, t1, acc1[o])));
        }
      }
    }

    if (ic + 1 < 32) WRITEX(cur ^ 1)
    __syncthreads();
  }
#undef LOADX
#undef WRITEX

  int p = ((z0 + lz) * 32 + (y0 + ly)) * 32 + x0 + 2 * lx2;
#pragma unroll
  for (int o = 0; o < 9; ++o) {
    float bia = bias[ocbase + o];
    *(float2*)&out[((size_t)b * 81 + ocbase + o) * 32768 + p] =
        make_float2(acc0[o] + bia, acc1[o] + bia);
  }
}

// ------------------------- tiled 3x3x3 conv (alpha; R6-proven) ------------
template <int OCG, bool REFLECT, bool NORM_IN>
__global__ __launch_bounds__(256) void conv3_kernel(
    const float* __restrict__ in,    // [B,IC,32768]
    const float* __restrict__ w,     // [OC_total,IC,27]
    const float* __restrict__ bias,  // [OC_total]
    const float* __restrict__ meanp, const float* __restrict__ rstdp,
    float* __restrict__ out,         // [B,OC_total,32768]
    int IC, int OC_total) {
  int bid = blockIdx.x;
  int tile = bid & 127;
  int rem = bid >> 7;
  int b = rem & 1;
  int og = rem >> 1;
  int tz = tile >> 4, ty = (tile >> 2) & 3, tx = tile & 3;
  int z0 = tz * 4, y0 = ty * 8, x0 = tx * 8;

  int tid = threadIdx.x;
  int lz = tid >> 6, ly = (tid >> 3) & 7, lx = tid & 7;

  __shared__ float tileS[2][720];  // [6][10][12]

  int s0 = tid, s1 = tid + 256, s2 = tid + 512;
  int g0 = 0, g1 = 0, g2 = 0;
  bool a0 = false, a1 = false, a2 = false;
  bool k0 = true, k1 = true, k2 = true;
#define DESC(S, G, A, K)                                            \
  {                                                                 \
    int hz = (S) / 120;                                             \
    int rr = (S) - hz * 120;                                        \
    int hy = rr / 12;                                               \
    int hx = rr - hy * 12;                                          \
    if ((S) < 720 && hx < 10) {                                     \
      int gz = z0 + hz - 1, gy = y0 + hy - 1, gx = x0 + hx - 1;     \
      if (REFLECT) {                                                \
        gz = gz < 0 ? -gz : (gz > 31 ? 62 - gz : gz);               \
        gy = gy < 0 ? -gy : (gy > 31 ? 62 - gy : gy);               \
        gx = gx < 0 ? -gx : (gx > 31 ? 62 - gx : gx);               \
      } else {                                                      \
        K = (unsigned)gz < 32u && (unsigned)gy < 32u &&             \
            (unsigned)gx < 32u;                                     \
        if (!(K)) { gz = 0; gy = 0; gx = 0; }                       \
      }                                                             \
      G = (gz * 32 + gy) * 32 + gx;                                 \
      A = true;                                                     \
    }                                                               \
  }
  DESC(s0, g0, a0, k0)
  DESC(s1, g1, a1, k1)
  DESC(s2, g2, a2, k2)
#undef DESC

  const float* inb = in + ((size_t)b * IC) * 32768;
  int ocbase = og * OCG;

  float acc[OCG];
#pragma unroll
  for (int o = 0; o < OCG; ++o) acc[o] = 0.f;

#define STAGE(BUF, IC2)                                             \
  {                                                                 \
    const float* ch = inb + (size_t)(IC2) * 32768;                  \
    float m = 0.f, r = 1.f;                                         \
    if (NORM_IN) {                                                  \
      m = meanp[b * IC + (IC2)];                                    \
      r = rstdp[b * IC + (IC2)];                                    \
    }                                                               \
    float v;                                                        \
    if (a0) {                                                       \
      v = k0 ? ch[g0] : 0.f;                                        \
      if (NORM_IN) { v = (v - m) * r; v = v >= 0.f ? v : 0.2f * v; }\
      tileS[BUF][s0] = v;                                           \
    }                                                               \
    if (a1) {                                                       \
      v = k1 ? ch[g1] : 0.f;                                        \
      if (NORM_IN) { v = (v - m) * r; v = v >= 0.f ? v : 0.2f * v; }\
      tileS[BUF][s1] = v;                                           \
    }                                                               \
    if (a2) {                                                       \
      v = k2 ? ch[g2] : 0.f;                                        \
      if (NORM_IN) { v = (v - m) * r; v = v >= 0.f ? v : 0.2f * v; }\
      tileS[BUF][s2] = v;                                           \
    }                                                               \
  }

  STAGE(0, 0)
  __syncthreads();

  int base = lz * 120 + ly * 12 + lx;
  for (int ic = 0; ic < IC; ++ic) {
    int cur = ic & 1;
    if (ic + 1 < IC) STAGE(cur ^ 1, ic + 1)

    float tap[27];
#pragma unroll
    for (int t = 0; t < 27; ++t) {
      int dz = t / 9, dy = (t / 3) % 3, dx = t % 3;
      tap[t] = tileS[cur][base + dz * 120 + dy * 12 + dx];
    }
    const float* wic = w + (size_t)ic * 27;
#pragma unroll
    for (int o = 0; o < OCG; ++o) {
      const float* wo = wic + (size_t)(ocbase + o) * IC * 27;  // wave-uniform
#pragma unroll
      for (int t = 0; t < 27; ++t) acc[o] = fmaf(wo[t], tap[t], acc[o]);
    }
    __syncthreads();
  }
#undef STAGE

  int p = ((z0 + lz) * 32 + (y0 + ly)) * 32 + (x0 + lx);
#pragma unroll
  for (int o = 0; o < OCG; ++o) {
    int oc = ocbase + o;
    out[((size_t)b * OC_total + oc) * 32768 + p] = acc[o] + bias[oc];
  }
}

// --------------------------------------------------------------- deform ----
__global__ __launch_bounds__(256) void deform_kernel(
    const float* __restrict__ f_pc,  // [B,32768,32]
    const float* __restrict__ offs,  // [B,81,32768]
    const float* __restrict__ wTd,   // [27,32,32] (k,i,o)
    float* __restrict__ part) {      // [3,B,32,32768]
  int bid = blockIdx.x;
  int kg = bid >> 8;                 // 0..2
  int tile = bid & 255;
  int vg = tile * 256 + threadIdx.x;
  int b = vg >> 15, p = vg & 32767;
  int z = p >> 10, y = (p >> 5) & 31, x = p & 31;
  const float* fb = f_pc + (((size_t)b) << 15) * 32;
  const float* ob = offs + (((size_t)b * 81) << 15);
  int kz = kg - 1;

  float acc[32];
#pragma unroll
  for (int o = 0; o < 32; ++o) acc[o] = 0.f;

  for (int kk = 0; kk < 9; ++kk) {
    int k = kg * 9 + kk;
    int ky = kk / 3 - 1, kx = kk % 3 - 1;

    float oz = ob[(size_t)(k * 3 + 0) * 32768 + p];
    float oy = ob[(size_t)(k * 3 + 1) * 32768 + p];
    float ox = ob[(size_t)(k * 3 + 2) * 32768 + p];
    float pz = (float)(z + kz) + oz;
    float py = (float)(y + ky) + oy;
    float px = (float)(x + kx) + ox;
    float fz = floorf(pz), fy = floorf(py), fxx = floorf(px);
    int iz0 = (int)fz, iy0 = (int)fy, ix0 = (int)fxx;
    float rz = pz - fz, ry = py - fy, rx = px - fxx;

    float v[32];
#pragma unroll
    for (int c = 0; c < 32; ++c) v[c] = 0.f;
#pragma unroll
    for (int corner = 0; corner < 8; ++corner) {
      int dz = corner >> 2, dy = (corner >> 1) & 1, dxx = corner & 1;
      int iz = iz0 + dz, iy = iy0 + dy, ix = ix0 + dxx;
      bool okb = (unsigned)iz < 32u && (unsigned)iy < 32u && (unsigned)ix < 32u;
      float wt = (dz ? rz : 1.f - rz) * (dy ? ry : 1.f - ry) *
                 (dxx ? rx : 1.f - rx);
      if (okb) {
        const float4* src =
            (const float4*)(fb + (size_t)((iz * 32 + iy) * 32 + ix) * 32);
#pragma unroll
        for (int q = 0; q < 8; ++q) {
          float4 u = src[q];
          v[q * 4 + 0] = fmaf(wt, u.x, v[q * 4 + 0]);
          v[q * 4 + 1] = fmaf(wt, u.y, v[q * 4 + 1]);
          v[q * 4 + 2] = fmaf(wt, u.z, v[q * 4 + 2]);
          v[q * 4 + 3] = fmaf(wt, u.w, v[q * 4 + 3]);
        }
      }
    }
    const float* wk = wTd + (size_t)k * 1024;  // wave-uniform base
#pragma unroll
    for (int i = 0; i < 32; ++i) {
      float vi = v[i];
      const float* wr = wk + i * 32;
#pragma unroll
      for (int o = 0; o < 32; ++o) acc[o] = fmaf(wr[o], vi, acc[o]);
    }
  }
  float* obp = part + (((size_t)kg * 2 + b) * 32) * 32768 + p;
#pragma unroll
  for (int o = 0; o < 32; ++o) obp[(size_t)o * 32768] = acc[o];
}

// ------------------- combine (3 partials + alpha) + partial stats ---------
__global__ __launch_bounds__(256) void combine_kernel(
    const float* __restrict__ part, const float* __restrict__ alpha,
    const float* __restrict__ dw, float* __restrict__ comb,
    float* __restrict__ partial) {   // [256][2]
  int blk = blockIdx.x;              // 64 bc x 4 quarters
  int bc = blk >> 2, qt = blk & 3;
  int b = bc >> 5;
  float d0 = dw[b * 2 + 0], d1 = dw[b * 2 + 1];
  const float* p0 = part + (size_t)(bc) * 32768;
  const float* p1 = part + (size_t)(64 + bc) * 32768;
  const float* p2 = part + (size_t)(128 + bc) * 32768;
  const float* al = alpha + (size_t)bc * 32768;
  float* cb = comb + (size_t)bc * 32768;
  float s = 0.f, ss = 0.f;
  int i0 = qt * 8192;
  for (int i = i0 + threadIdx.x; i < i0 + 8192; i += 256) {
    float v = d0 * (p0[i] + p1[i] + p2[i]) + d1 * al[i];
    cb[i] = v;
    s += v; ss += v * v;
  }
  for (int o = 32; o; o >>= 1) {
    s += __shfl_down(s, o);
    ss += __shfl_down(ss, o);
  }
  __shared__ float sb[4], ssb[4];
  int wid = threadIdx.x >> 6, lane = threadIdx.x & 63;
  if (lane == 0) { sb[wid] = s; ssb[wid] = ss; }
  __syncthreads();
  if (threadIdx.x == 0) {
    float S = 0.f, SS = 0.f;
    for (int w = 0; w < 4; ++w) { S += sb[w]; SS += ssb[w]; }
    partial[blk * 2 + 0] = S;
    partial[blk * 2 + 1] = SS;
  }
}

__global__ void finalize_kernel(const float* __restrict__ partial,
                                float* __restrict__ mean, float* __restrict__ rstd) {
  int t = threadIdx.x;  // 64 = bc
  if (t < 64) {
    float S = 0.f, SS = 0.f;
    for (int q = 0; q < 4; ++q) {
      S += partial[(t * 4 + q) * 2 + 0];
      SS += partial[(t * 4 + q) * 2 + 1];
    }
    float m = S * (1.f / 32768.f);
    float var = SS * (1.f / 32768.f) - m * m;
    mean[t] = m;
    rstd[t] = rsqrtf(var + EPS);
  }
}

// ------------------- fused inorm+lrelu+1x1 (32->32), o-split x4 -----------
__global__ __launch_bounds__(256) void last_conv_kernel(
    const float* __restrict__ comb, const float* __restrict__ w,  // [32,32]
    const float* __restrict__ bias,
    const float* __restrict__ meanp, const float* __restrict__ rstdp,
    float* __restrict__ out) {
  int og = blockIdx.x >> 8;
  int chunk = blockIdx.x & 255;
  int vg = chunk * 256 + threadIdx.x;
  int b = vg >> 15, p = vg & 32767;
  float acc[8];
#pragma unroll
  for (int o = 0; o < 8; ++o) acc[o] = 0.f;
  const float* cb = comb + ((size_t)b * 32) * 32768;
  const float* wg = w + (size_t)og * 8 * 32;
  for (int i = 0; i < 32; ++i) {
    float v = cb[(size_t)i * 32768 + p];
    float m = meanp[b * 32 + i], r = rstdp[b * 32 + i];
    v = (v - m) * r;
    v = v >= 0.f ? v : 0.2f * v;
#pragma unroll
    for (int o = 0; o < 8; ++o) acc[o] = fmaf(wg[o * 32 + i], v, acc[o]);
  }
#pragma unroll
  for (int o = 0; o < 8; ++o)
    out[((size_t)b * 32 + og * 8 + o) * 32768 + p] = acc[o] + bias[og * 8 + o];
}

// ---------------------------------------------------------------- launch ---
extern "C" void kernel_launch(void* const* d_in, const int* in_sizes, int n_in,
                              void* d_out, int out_size, void* d_ws, size_t ws_size,
                              hipStream_t stream) {
  (void)in_sizes; (void)n_in; (void)out_size; (void)ws_size;
  const float* x       = (const float*)d_in[0];
  const float* w_first = (const float*)d_in[1];
  const float* b_first = (const float*)d_in[2];
  const float* w_na    = (const float*)d_in[3];
  const float* b_na    = (const float*)d_in[4];
  const float* w_last  = (const float*)d_in[5];
  const float* b_last  = (const float*)d_in[6];
  const float* w_fc1   = (const float*)d_in[7];
  const float* b_fc1   = (const float*)d_in[8];
  const float* w_fc2   = (const float*)d_in[9];
  const float* b_fc2   = (const float*)d_in[10];
  const float* w_off   = (const float*)d_in[11];
  const float* b_off   = (const float*)d_in[12];
  const float* w_def   = (const float*)d_in[13];
  float* out = (float*)d_out;

  float* ws = (float*)d_ws;
  float* mean_x  = ws + 0;        // 128
  float* rstd_x  = ws + 128;      // 128
  float* dwp     = ws + 256;      // 4
  float* mean_f  = ws + 272;      // 64
  float* rstd_f  = ws + 336;      // 64
  float* mean_c  = ws + 400;      // 64
  float* rstd_c  = ws + 464;      // 64
  float* partial = ws + 528;      // 512
  size_t off0 = 2048;
  float* wTd   = ws + off0;                       // 27,648
  float* f_cp  = ws + off0 + 28672;               // 2,097,152
  float* f_pc  = f_cp + 2097152;                  // 2,097,152
  float* offb  = f_pc + 2097152;                  // 5,308,416
  float* alpha = offb + 5308416;                  // 2,097,152
  float* part  = alpha + 2097152;                 // 6,291,456
  float* comb  = part + 6291456;                  // 2,097,152

  // 1. stats of x (also SE global-avg-pool) + weight transpose prep
  hipLaunchKernelGGL(stats_kernel, dim3(128), dim3(256), 0, stream, x, mean_x, rstd_x);
  hipLaunchKernelGGL(prep_wdef, dim3(108), dim3(256), 0, stream, w_def, wTd);
  // 2. SE gate -> dw
  hipLaunchKernelGGL(se_kernel, dim3(1), dim3(64), 0, stream,
                     mean_x, w_fc1, b_fc1, w_fc2, b_fc2, dwp);
  // 3. f = conv1x1(lrelu(inorm(x))), two layouts, o-split x4
  hipLaunchKernelGGL(first_conv_kernel, dim3(1024), dim3(256), 0, stream,
                     x, w_first, b_first, mean_x, rstd_x, f_cp, f_pc);
  // 4. stats of f
  hipLaunchKernelGGL(stats_kernel, dim3(64), dim3(256), 0, stream, f_cp, mean_f, rstd_f);
  // 5. off = conv3x3x3(f), zero pad, 32->81 (x-paired kernel, 1152 blocks)
  hipLaunchKernelGGL(conv3_off_kernel, dim3(1152), dim3(256), 0, stream,
                     f_cp, w_off, b_off, offb);
  // 6. alpha = conv3x3x3(lrelu(inorm(f))), reflect pad (R6-proven, 1024 blocks)
  hipLaunchKernelGGL((conv3_kernel<8, true, true>), dim3(128 * 2 * 4), dim3(256), 0, stream,
                     f_cp, w_na, b_na, mean_f, rstd_f, alpha, 32, 32);
  // 7. belta partials (deform), SGPR-weight matmul, no LDS
  hipLaunchKernelGGL(deform_kernel, dim3(768), dim3(256), 0, stream,
                     f_pc, offb, wTd, part);
  // 8. comb = dw0*belta + dw1*alpha, partial stats
  hipLaunchKernelGGL(combine_kernel, dim3(256), dim3(256), 0, stream,
                     part, alpha, dwp, comb, partial);
  hipLaunchKernelGGL(finalize_kernel, dim3(1), dim3(64), 0, stream,
                     partial, mean_c, rstd_c);
  // 9. out = conv1x1(lrelu(inorm(comb)))
  hipLaunchKernelGGL(last_conv_kernel, dim3(1024), dim3(256), 0, stream,
                     comb, w_last, b_last, mean_c, rstd_c, out);
}

// Round 12
// 623.099 us; speedup vs baseline: 1.4772x; 1.3009x over previous
//
#include <hip/hip_runtime.h>
#include <hip/hip_bf16.h>

#define EPS 1e-5f

// ---------------------------------------------------------------- stats ----
__global__ __launch_bounds__(256) void stats_kernel(
    const float* __restrict__ buf, float* __restrict__ mean,
    float* __restrict__ rstd) {
  int bc = blockIdx.x;
  const float* ch = buf + (size_t)bc * 32768;
  float s = 0.f, ss = 0.f;
  for (int i = threadIdx.x; i < 32768; i += 256) {
    float v = ch[i];
    s += v; ss += v * v;
  }
  for (int o = 32; o; o >>= 1) {
    s += __shfl_down(s, o);
    ss += __shfl_down(ss, o);
  }
  __shared__ float sb[4], ssb[4];
  int wid = threadIdx.x >> 6, lane = threadIdx.x & 63;
  if (lane == 0) { sb[wid] = s; ssb[wid] = ss; }
  __syncthreads();
  if (threadIdx.x == 0) {
    float S = 0.f, SS = 0.f;
    for (int w = 0; w < 4; ++w) { S += sb[w]; SS += ssb[w]; }
    float m = S * (1.f / 32768.f);
    float var = SS * (1.f / 32768.f) - m * m;
    mean[bc] = m;
    rstd[bc] = rsqrtf(var + EPS);
  }
}

// ------------------------------------------------------------------- SE ----
__global__ void se_kernel(const float* __restrict__ mean_x,
                          const float* __restrict__ w1, const float* __restrict__ b1,
                          const float* __restrict__ w2, const float* __restrict__ b2,
                          float* __restrict__ dw) {
  __shared__ float hbuf[32];
  int t = threadIdx.x;
  if (t < 32) {
    int b = t >> 4, j = t & 15;
    float a = b1[j];
    for (int c = 0; c < 64; ++c) a += mean_x[b * 64 + c] * w1[j * 64 + c];
    hbuf[t] = a >= 0.f ? a : 0.2f * a;
  }
  __syncthreads();
  if (t < 2) {
    int b = t;
    float l0 = b2[0], l1 = b2[1];
    for (int j = 0; j < 16; ++j) {
      float h = hbuf[b * 16 + j];
      l0 += h * w2[j];
      l1 += h * w2[16 + j];
    }
    float m = fmaxf(l0, l1);
    float e0 = __expf(l0 - m), e1 = __expf(l1 - m);
    float inv = 1.f / (e0 + e1);
    dw[b * 2 + 0] = e0 * inv;
    dw[b * 2 + 1] = e1 * inv;
  }
}

// --------------------------------------------- transpose w_def -> [k][i][o]
__global__ __launch_bounds__(256) void prep_wdef(const float* __restrict__ w_def,
                                                 float* __restrict__ wTd) {
  int idx = blockIdx.x * 256 + threadIdx.x;  // 27*32*32 = 27648
  if (idx < 27648) {
    int o = idx & 31, rest = idx >> 5;
    int i = rest & 31, k = rest >> 5;
    wTd[idx] = w_def[(size_t)(o * 32 + i) * 27 + k];
  }
}

// ------------------------------- transpose w_off [81,32,27] -> [27][32][81]
__global__ __launch_bounds__(256) void prep_woff(const float* __restrict__ w_off,
                                                 float* __restrict__ wT) {
  int idx = blockIdx.x * 256 + threadIdx.x;  // 27*32*81 = 69984
  if (idx < 69984) {
    int o = idx % 81, rest = idx / 81;
    int i = rest & 31, t = rest >> 5;
    wT[idx] = w_off[(size_t)(o * 32 + i) * 27 + t];
  }
}

// -------------------------------- transpose w_na [32,32,27] -> [27][32][32]
__global__ __launch_bounds__(256) void prep_wna(const float* __restrict__ w_na,
                                                float* __restrict__ wT) {
  int idx = blockIdx.x * 256 + threadIdx.x;  // 27*32*32 = 27648
  if (idx < 27648) {
    int o = idx & 31, rest = idx >> 5;
    int i = rest & 31, t = rest >> 5;
    wT[idx] = w_na[(size_t)(o * 32 + i) * 27 + t];
  }
}

// ------------------- fused inorm+lrelu+1x1 (64->32), o-split x4 -----------
__global__ __launch_bounds__(256) void first_conv_kernel(
    const float* __restrict__ x, const float* __restrict__ w,   // [32,64]
    const float* __restrict__ bias,
    const float* __restrict__ meanp, const float* __restrict__ rstdp,
    float* __restrict__ f_cp, float* __restrict__ f_pc) {
  int og = blockIdx.x >> 8;
  int chunk = blockIdx.x & 255;
  int vg = chunk * 256 + threadIdx.x;
  int b = vg >> 15, p = vg & 32767;
  float acc[8];
#pragma unroll
  for (int o = 0; o < 8; ++o) acc[o] = 0.f;
  const float* xb = x + ((size_t)b * 64) * 32768;
  const float* wg = w + (size_t)og * 8 * 64;
  for (int i = 0; i < 64; ++i) {
    float v = xb[(size_t)i * 32768 + p];
    float m = meanp[b * 64 + i], r = rstdp[b * 64 + i];
    v = (v - m) * r;
    v = v >= 0.f ? v : 0.2f * v;
#pragma unroll
    for (int o = 0; o < 8; ++o) acc[o] = fmaf(wg[o * 64 + i], v, acc[o]);
  }
#pragma unroll
  for (int o = 0; o < 8; ++o) {
    acc[o] += bias[og * 8 + o];
    f_cp[((size_t)b * 32 + og * 8 + o) * 32768 + p] = acc[o];
  }
  float4 v0 = make_float4(acc[0], acc[1], acc[2], acc[3]);
  float4 v1 = make_float4(acc[4], acc[5], acc[6], acc[7]);
  float* pc = f_pc + ((size_t)b * 32768 + p) * 32 + og * 8;
  *(float4*)pc = v0;
  *(float4*)(pc + 4) = v1;
}

// ------------------------- f_norm = lrelu(inorm(f)) elementwise -----------
__global__ __launch_bounds__(256) void norm_f_kernel(
    const float* __restrict__ f_cp, const float* __restrict__ meanp,
    const float* __restrict__ rstdp, float* __restrict__ f_norm) {
  int i4 = blockIdx.x * 256 + threadIdx.x;   // 524288 float4 groups
  int bc = (i4 * 4) >> 15;
  float m = meanp[bc], r = rstdp[bc];
  float4 v = ((const float4*)f_cp)[i4];
  float4 o;
  o.x = (v.x - m) * r; o.x = o.x >= 0.f ? o.x : 0.2f * o.x;
  o.y = (v.y - m) * r; o.y = o.y >= 0.f ? o.y : 0.2f * o.y;
  o.z = (v.z - m) * r; o.z = o.z >= 0.f ? o.z : 0.2f * o.z;
  o.w = (v.w - m) * r; o.w = o.w >= 0.f ? o.w : 0.2f * o.w;
  ((float4*)f_norm)[i4] = o;
}

// ---------------- implicit-GEMM direct 3x3x3 conv (no LDS, no barriers) ---
// Thread-per-position. Per tap t: offset+validity computed once; inner loop
// over 32 ic reads coalesced from L1/L2 (27x line reuse), weights from
// pre-transposed wT[27][32][OCT] via wave-uniform scalar loads (o-contig).
// REFLECT: reflect-padded offsets (input pre-normalized f_norm).
template <int OCG, int OCT, bool REFLECT>
__global__ __launch_bounds__(256) void conv3_direct_kernel(
    const float* __restrict__ in,    // [B,32,32768]
    const float* __restrict__ wT,    // [27,32,OCT]
    const float* __restrict__ bias,  // [OCT]
    float* __restrict__ out) {       // [B,OCT,32768]
  int og = blockIdx.x >> 8;
  int chunk = blockIdx.x & 255;
  int vg = chunk * 256 + threadIdx.x;
  int b = vg >> 15, p = vg & 32767;
  int z = p >> 10, y = (p >> 5) & 31, x = p & 31;
  const float* base = in + ((size_t)b * 32) * 32768;

  float acc[OCG];
#pragma unroll
  for (int o = 0; o < OCG; ++o) acc[o] = 0.f;

  for (int t = 0; t < 27; ++t) {
    int dz = t / 9, dy = (t / 3) % 3, dx = t % 3;
    int zz = z + dz - 1, yy = y + dy - 1, xx = x + dx - 1;
    bool valid = true;
    if (REFLECT) {
      zz = zz < 0 ? -zz : (zz > 31 ? 62 - zz : zz);
      yy = yy < 0 ? -yy : (yy > 31 ? 62 - yy : yy);
      xx = xx < 0 ? -xx : (xx > 31 ? 62 - xx : xx);
    } else {
      valid = (unsigned)zz < 32u && (unsigned)yy < 32u && (unsigned)xx < 32u;
      if (!valid) { zz = 0; yy = 0; xx = 0; }
    }
    int off = (zz * 32 + yy) * 32 + xx;
    const float* cptr = base + off;
    const float* wt = wT + (size_t)t * 32 * OCT + og * OCG;  // wave-uniform
#pragma unroll 4
    for (int i = 0; i < 32; ++i) {
      float v = cptr[(size_t)i << 15];
      if (!REFLECT) v = valid ? v : 0.f;
#pragma unroll
      for (int o = 0; o < OCG; ++o)
        acc[o] = fmaf(wt[i * OCT + o], v, acc[o]);
    }
  }
  float* op = out + ((size_t)b * OCT + og * OCG) * 32768 + p;
#pragma unroll
  for (int o = 0; o < OCG; ++o)
    op[(size_t)o * 32768] = acc[o] + bias[og * OCG + o];
}

// --------------------------------------------------------------- deform ----
__global__ __launch_bounds__(256) void deform_kernel(
    const float* __restrict__ f_pc,  // [B,32768,32]
    const float* __restrict__ offs,  // [B,81,32768]
    const float* __restrict__ wTd,   // [27,32,32] (k,i,o)
    float* __restrict__ part) {      // [3,B,32,32768]
  int bid = blockIdx.x;
  int kg = bid >> 8;                 // 0..2
  int tile = bid & 255;
  int vg = tile * 256 + threadIdx.x;
  int b = vg >> 15, p = vg & 32767;
  int z = p >> 10, y = (p >> 5) & 31, x = p & 31;
  const float* fb = f_pc + (((size_t)b) << 15) * 32;
  const float* ob = offs + (((size_t)b * 81) << 15);
  int kz = kg - 1;

  float acc[32];
#pragma unroll
  for (int o = 0; o < 32; ++o) acc[o] = 0.f;

  for (int kk = 0; kk < 9; ++kk) {
    int k = kg * 9 + kk;
    int ky = kk / 3 - 1, kx = kk % 3 - 1;

    float oz = ob[(size_t)(k * 3 + 0) * 32768 + p];
    float oy = ob[(size_t)(k * 3 + 1) * 32768 + p];
    float ox = ob[(size_t)(k * 3 + 2) * 32768 + p];
    float pz = (float)(z + kz) + oz;
    float py = (float)(y + ky) + oy;
    float px = (float)(x + kx) + ox;
    float fz = floorf(pz), fy = floorf(py), fxx = floorf(px);
    int iz0 = (int)fz, iy0 = (int)fy, ix0 = (int)fxx;
    float rz = pz - fz, ry = py - fy, rx = px - fxx;

    float v[32];
#pragma unroll
    for (int c = 0; c < 32; ++c) v[c] = 0.f;
#pragma unroll
    for (int corner = 0; corner < 8; ++corner) {
      int dz = corner >> 2, dy = (corner >> 1) & 1, dxx = corner & 1;
      int iz = iz0 + dz, iy = iy0 + dy, ix = ix0 + dxx;
      bool okb = (unsigned)iz < 32u && (unsigned)iy < 32u && (unsigned)ix < 32u;
      float wt = (dz ? rz : 1.f - rz) * (dy ? ry : 1.f - ry) *
                 (dxx ? rx : 1.f - rx);
      if (okb) {
        const float4* src =
            (const float4*)(fb + (size_t)((iz * 32 + iy) * 32 + ix) * 32);
#pragma unroll
        for (int q = 0; q < 8; ++q) {
          float4 u = src[q];
          v[q * 4 + 0] = fmaf(wt, u.x, v[q * 4 + 0]);
          v[q * 4 + 1] = fmaf(wt, u.y, v[q * 4 + 1]);
          v[q * 4 + 2] = fmaf(wt, u.z, v[q * 4 + 2]);
          v[q * 4 + 3] = fmaf(wt, u.w, v[q * 4 + 3]);
        }
      }
    }
    const float* wk = wTd + (size_t)k * 1024;  // wave-uniform base
#pragma unroll
    for (int i = 0; i < 32; ++i) {
      float vi = v[i];
      const float* wr = wk + i * 32;
#pragma unroll
      for (int o = 0; o < 32; ++o) acc[o] = fmaf(wr[o], vi, acc[o]);
    }
  }
  float* obp = part + (((size_t)kg * 2 + b) * 32) * 32768 + p;
#pragma unroll
  for (int o = 0; o < 32; ++o) obp[(size_t)o * 32768] = acc[o];
}

// ------------------- combine (3 partials + alpha) + partial stats ---------
__global__ __launch_bounds__(256) void combine_kernel(
    const float* __restrict__ part, const float* __restrict__ alpha,
    const float* __restrict__ dw, float* __restrict__ comb,
    float* __restrict__ partial) {   // [256][2]
  int blk = blockIdx.x;              // 64 bc x 4 quarters
  int bc = blk >> 2, qt = blk & 3;
  int b = bc >> 5;
  float d0 = dw[b * 2 + 0], d1 = dw[b * 2 + 1];
  const float* p0 = part + (size_t)(bc) * 32768;
  const float* p1 = part + (size_t)(64 + bc) * 32768;
  const float* p2 = part + (size_t)(128 + bc) * 32768;
  const float* al = alpha + (size_t)bc * 32768;
  float* cb = comb + (size_t)bc * 32768;
  float s = 0.f, ss = 0.f;
  int i0 = qt * 8192;
  for (int i = i0 + threadIdx.x; i < i0 + 8192; i += 256) {
    float v = d0 * (p0[i] + p1[i] + p2[i]) + d1 * al[i];
    cb[i] = v;
    s += v; ss += v * v;
  }
  for (int o = 32; o; o >>= 1) {
    s += __shfl_down(s, o);
    ss += __shfl_down(ss, o);
  }
  __shared__ float sb[4], ssb[4];
  int wid = threadIdx.x >> 6, lane = threadIdx.x & 63;
  if (lane == 0) { sb[wid] = s; ssb[wid] = ss; }
  __syncthreads();
  if (threadIdx.x == 0) {
    float S = 0.f, SS = 0.f;
    for (int w = 0; w < 4; ++w) { S += sb[w]; SS += ssb[w]; }
    partial[blk * 2 + 0] = S;
    partial[blk * 2 + 1] = SS;
  }
}

__global__ void finalize_kernel(const float* __restrict__ partial,
                                float* __restrict__ mean, float* __restrict__ rstd) {
  int t = threadIdx.x;  // 64 = bc
  if (t < 64) {
    float S = 0.f, SS = 0.f;
    for (int q = 0; q < 4; ++q) {
      S += partial[(t * 4 + q) * 2 + 0];
      SS += partial[(t * 4 + q) * 2 + 1];
    }
    float m = S * (1.f / 32768.f);
    float var = SS * (1.f / 32768.f) - m * m;
    mean[t] = m;
    rstd[t] = rsqrtf(var + EPS);
  }
}

// ------------------- fused inorm+lrelu+1x1 (32->32), o-split x4 -----------
__global__ __launch_bounds__(256) void last_conv_kernel(
    const float* __restrict__ comb, const float* __restrict__ w,  // [32,32]
    const float* __restrict__ bias,
    const float* __restrict__ meanp, const float* __restrict__ rstdp,
    float* __restrict__ out) {
  int og = blockIdx.x >> 8;
  int chunk = blockIdx.x & 255;
  int vg = chunk * 256 + threadIdx.x;
  int b = vg >> 15, p = vg & 32767;
  float acc[8];
#pragma unroll
  for (int o = 0; o < 8; ++o) acc[o] = 0.f;
  const float* cb = comb + ((size_t)b * 32) * 32768;
  const float* wg = w + (size_t)og * 8 * 32;
  for (int i = 0; i < 32; ++i) {
    float v = cb[(size_t)i * 32768 + p];
    float m = meanp[b * 32 + i], r = rstdp[b * 32 + i];
    v = (v - m) * r;
    v = v >= 0.f ? v : 0.2f * v;
#pragma unroll
    for (int o = 0; o < 8; ++o) acc[o] = fmaf(wg[o * 32 + i], v, acc[o]);
  }
#pragma unroll
  for (int o = 0; o < 8; ++o)
    out[((size_t)b * 32 + og * 8 + o) * 32768 + p] = acc[o] + bias[og * 8 + o];
}

// ---------------------------------------------------------------- launch ---
extern "C" void kernel_launch(void* const* d_in, const int* in_sizes, int n_in,
                              void* d_out, int out_size, void* d_ws, size_t ws_size,
                              hipStream_t stream) {
  (void)in_sizes; (void)n_in; (void)out_size; (void)ws_size;
  const float* x       = (const float*)d_in[0];
  const float* w_first = (const float*)d_in[1];
  const float* b_first = (const float*)d_in[2];
  const float* w_na    = (const float*)d_in[3];
  const float* b_na    = (const float*)d_in[4];
  const float* w_last  = (const float*)d_in[5];
  const float* b_last  = (const float*)d_in[6];
  const float* w_fc1   = (const float*)d_in[7];
  const float* b_fc1   = (const float*)d_in[8];
  const float* w_fc2   = (const float*)d_in[9];
  const float* b_fc2   = (const float*)d_in[10];
  const float* w_off   = (const float*)d_in[11];
  const float* b_off   = (const float*)d_in[12];
  const float* w_def   = (const float*)d_in[13];
  float* out = (float*)d_out;

  float* ws = (float*)d_ws;
  float* mean_x  = ws + 0;        // 128
  float* rstd_x  = ws + 128;      // 128
  float* dwp     = ws + 256;      // 4
  float* mean_f  = ws + 272;      // 64
  float* rstd_f  = ws + 336;      // 64
  float* mean_c  = ws + 400;      // 64
  float* rstd_c  = ws + 464;      // 64
  float* partial = ws + 528;      // 512
  size_t off0 = 2048;
  float* wTd    = ws + off0;                      // 27,648 (slot 28,672)
  float* wT_off = wTd + 28672;                    // 69,984 (slot 71,680)
  float* wT_na  = wT_off + 71680;                 // 27,648 (slot 28,672)
  float* f_cp   = wT_na + 28672;                  // 2,097,152
  float* f_pc   = f_cp + 2097152;                 // 2,097,152
  float* offb   = f_pc + 2097152;                 // 5,308,416
  float* alpha  = offb + 5308416;                 // 2,097,152
  float* part   = alpha + 2097152;                // 6,291,456
  float* comb   = part + 6291456;                 // 2,097,152
  // f_norm aliases part: alpha-conv (reads f_norm) completes before
  // deform (writes part) in stream order.
  float* f_norm = part;

  // 1. stats of x (also SE global-avg-pool) + weight transposes
  hipLaunchKernelGGL(stats_kernel, dim3(128), dim3(256), 0, stream, x, mean_x, rstd_x);
  hipLaunchKernelGGL(prep_wdef, dim3(108), dim3(256), 0, stream, w_def, wTd);
  hipLaunchKernelGGL(prep_woff, dim3(274), dim3(256), 0, stream, w_off, wT_off);
  hipLaunchKernelGGL(prep_wna, dim3(108), dim3(256), 0, stream, w_na, wT_na);
  // 2. SE gate -> dw
  hipLaunchKernelGGL(se_kernel, dim3(1), dim3(64), 0, stream,
                     mean_x, w_fc1, b_fc1, w_fc2, b_fc2, dwp);
  // 3. f = conv1x1(lrelu(inorm(x))), two layouts, o-split x4
  hipLaunchKernelGGL(first_conv_kernel, dim3(1024), dim3(256), 0, stream,
                     x, w_first, b_first, mean_x, rstd_x, f_cp, f_pc);
  // 4. stats of f, then f_norm = lrelu(inorm(f))
  hipLaunchKernelGGL(stats_kernel, dim3(64), dim3(256), 0, stream, f_cp, mean_f, rstd_f);
  hipLaunchKernelGGL(norm_f_kernel, dim3(2048), dim3(256), 0, stream,
                     f_cp, mean_f, rstd_f, f_norm);
  // 5. off = conv3x3x3(f), zero pad, 32->81 (direct, 9 og, 2304 blocks)
  hipLaunchKernelGGL((conv3_direct_kernel<9, 81, false>), dim3(2304), dim3(256), 0, stream,
                     f_cp, wT_off, b_off, offb);
  // 6. alpha = conv3x3x3(f_norm), reflect pad (direct, 4 og, 1024 blocks)
  hipLaunchKernelGGL((conv3_direct_kernel<8, 32, true>), dim3(1024), dim3(256), 0, stream,
                     f_norm, wT_na, b_na, alpha);
  // 7. belta partials (deform), SGPR-weight matmul, no LDS
  hipLaunchKernelGGL(deform_kernel, dim3(768), dim3(256), 0, stream,
                     f_pc, offb, wTd, part);
  // 8. comb = dw0*belta + dw1*alpha, partial stats
  hipLaunchKernelGGL(combine_kernel, dim3(256), dim3(256), 0, stream,
                     part, alpha, dwp, comb, partial);
  hipLaunchKernelGGL(finalize_kernel, dim3(1), dim3(64), 0, stream,
                     partial, mean_c, rstd_c);
  // 9. out = conv1x1(lrelu(inorm(comb)))
  hipLaunchKernelGGL(last_conv_kernel, dim3(1024), dim3(256), 0, stream,
                     comb, w_last, b_last, mean_c, rstd_c, out);
}